// Round 5
// baseline (363.767 us; speedup 1.0000x reference)
//
#include <hip/hip_runtime.h>
#include <hip/hip_bf16.h>
#include <stdint.h>

typedef __attribute__((ext_vector_type(8))) short bf16x8;
typedef __attribute__((ext_vector_type(4))) float f32x4;

#define DEVINL __device__ __forceinline__

// ---------------------------------------------------------------- helpers
DEVINL unsigned short f2bf(float f) {
  unsigned int u = __builtin_bit_cast(unsigned int, f);
  u += 0x7fffu + ((u >> 16) & 1u);   // RNE
  return (unsigned short)(u >> 16);
}

DEVINL void gload_lds16(const void* gptr, void* lptr) {
  // dest is wave-uniform base + lane*16 (we pass per-lane base+lane*16; HW/readfirstlane takes lane0)
  __builtin_amdgcn_global_load_lds(
      (__attribute__((address_space(1))) void*)(uintptr_t)gptr,
      (__attribute__((address_space(3))) void*)(uint32_t)(uintptr_t)lptr,
      16, 0, 0);
}

// ---------------------------------------------------------------- fp32 -> bf16
__global__ __launch_bounds__(256) void cvt_bf16_kernel(const float* __restrict__ src,
                                                       unsigned short* __restrict__ dst,
                                                       int n) {
  int i = (blockIdx.x * 256 + threadIdx.x) * 4;
  if (i >= n) return;
  const float4 v = *reinterpret_cast<const float4*>(src + i);
  ushort4 o;
  o.x = f2bf(v.x); o.y = f2bf(v.y); o.z = f2bf(v.z); o.w = f2bf(v.w);
  *reinterpret_cast<ushort4*>(dst + i) = o;
}

// ---------------------------------------------------------------- fused QKV GEMM
// out[m][n] = sum_k xbf[m][k] * wcat[n][k] + bias, m in [0,4096), n in [0,3072)
// n -> which = n/1024 (0:q 1:k 2:v), co = n%1024, h = co/64, d = co%64
__global__ __launch_bounds__(256) void qkv_gemm_kernel(
    const unsigned short* __restrict__ xbf,   // [4096][1024] bf16
    const unsigned short* __restrict__ wcat,  // [3072][1024] bf16
    const float* __restrict__ bq,
    const float* __restrict__ bk,
    const float* __restrict__ bv,
    float* __restrict__ out_k,                // [B,H,T,D] f32
    float* __restrict__ out_v,                // [B,H,T,D] f32
    unsigned short* __restrict__ qbf,         // [B,H,T,D] bf16
    unsigned short* __restrict__ kbf,         // [B,H,T,D] bf16
    unsigned short* __restrict__ vtr)         // [B,H,D,T] bf16
{
  __shared__ unsigned short As[128 * 32];
  __shared__ unsigned short Bs[128 * 32];
  const int t = threadIdx.x;
  const int l = t & 63;
  const int w = t >> 6;
  const int lr = l & 15, lg = l >> 4;
  const int wr = w >> 1, wc = w & 1;
  const int m0 = blockIdx.y * 128;
  const int n0 = blockIdx.x * 128;

  // staging geometry: slot s covers elements [s*8, s*8+8) of the 128x32 tile
  const int row0 = (t * 8) >> 5, col0 = (t * 8) & 31;
  const int row1 = ((256 + t) * 8) >> 5, col1 = ((256 + t) * 8) & 31;
  const unsigned short* aG0 = xbf + (m0 + row0) * 1024 + col0;
  const unsigned short* aG1 = xbf + (m0 + row1) * 1024 + col1;
  const unsigned short* bG0 = wcat + (n0 + row0) * 1024 + col0;
  const unsigned short* bG1 = wcat + (n0 + row1) * 1024 + col1;
  unsigned short* aL0 = As + t * 8;
  unsigned short* aL1 = As + (256 + t) * 8;
  unsigned short* bL0 = Bs + t * 8;
  unsigned short* bL1 = Bs + (256 + t) * 8;

  const int aOff = (wr * 64 + lr) * 32 + 8 * lg;
  const int bOff = (wc * 64 + lr) * 32 + 8 * lg;

  f32x4 acc[4][4];
  const f32x4 zf = {0.f, 0.f, 0.f, 0.f};
#pragma unroll
  for (int i = 0; i < 4; i++)
#pragma unroll
    for (int j = 0; j < 4; j++) acc[i][j] = zf;

  for (int kt = 0; kt < 1024; kt += 32) {
    gload_lds16(aG0 + kt, aL0);
    gload_lds16(aG1 + kt, aL1);
    gload_lds16(bG0 + kt, bL0);
    gload_lds16(bG1 + kt, bL1);
    __syncthreads();
    bf16x8 af[4], bfr[4];
#pragma unroll
    for (int mi = 0; mi < 4; mi++)
      af[mi] = *reinterpret_cast<const bf16x8*>(As + aOff + mi * 16 * 32);
#pragma unroll
    for (int ni = 0; ni < 4; ni++)
      bfr[ni] = *reinterpret_cast<const bf16x8*>(Bs + bOff + ni * 16 * 32);
#pragma unroll
    for (int mi = 0; mi < 4; mi++)
#pragma unroll
      for (int ni = 0; ni < 4; ni++)
        acc[mi][ni] = __builtin_amdgcn_mfma_f32_16x16x32_bf16(af[mi], bfr[ni], acc[mi][ni], 0, 0, 0);
    __syncthreads();
  }

  const int which = n0 >> 10;
  const float* bias = (which == 0) ? bq : (which == 1) ? bk : bv;
#pragma unroll
  for (int ni = 0; ni < 4; ni++) {
    const int n = n0 + wc * 64 + ni * 16 + lr;
    const int co = n & 1023;
    const float bb = bias[co];
    const int h = co >> 6, d = co & 63;
#pragma unroll
    for (int mi = 0; mi < 4; mi++) {
#pragma unroll
      for (int r = 0; r < 4; r++) {
        const int m = m0 + wr * 64 + mi * 16 + 4 * lg + r;
        const float val = acc[mi][ni][r] + bb;
        const int bb_ = m >> 11, tt = m & 2047;
        const int bh = bb_ * 16 + h;
        const int idx = (bh * 2048 + tt) * 64 + d;
        if (which == 0) {
          qbf[idx] = f2bf(val);
        } else if (which == 1) {
          out_k[idx] = val;
          kbf[idx] = f2bf(val);
        } else {
          out_v[idx] = val;
          vtr[(bh * 64 + d) * 2048 + tt] = f2bf(val);
        }
      }
    }
  }
}

// ---------------------------------------------------------------- flash attention
// 4 waves/block; wave w owns 16 q-rows; KV-block = 32; online softmax.
__global__ __launch_bounds__(256) void attn_kernel(
    const unsigned short* __restrict__ qbf,  // [BH][T][D] bf16
    const unsigned short* __restrict__ kbf,  // [BH][T][D] bf16
    const unsigned short* __restrict__ vtr,  // [BH][D][T] bf16
    float* __restrict__ y)                   // [B,T,C] f32
{
  __shared__ unsigned short pbuf[4][16 * 32];
  const int w = threadIdx.x >> 6, l = threadIdx.x & 63;
  const int lr = l & 15, lg = l >> 4;
  const int qt = blockIdx.x, bh = blockIdx.y;
  const int b = bh >> 4, h = bh & 15;
  const int qbase = qt * 64 + w * 16;
  const unsigned short* Q = qbf + bh * 2048 * 64;
  const unsigned short* K = kbf + bh * 2048 * 64;
  const unsigned short* V = vtr + bh * 64 * 2048;
  unsigned short* pb = pbuf[w];

  const bf16x8 qf0 = *reinterpret_cast<const bf16x8*>(Q + (qbase + lr) * 64 + 8 * lg);
  const bf16x8 qf1 = *reinterpret_cast<const bf16x8*>(Q + (qbase + lr) * 64 + 32 + 8 * lg);

  float mi[4], li[4];
  f32x4 acc[4];
  const f32x4 zf = {0.f, 0.f, 0.f, 0.f};
#pragma unroll
  for (int r = 0; r < 4; r++) { mi[r] = -1e30f; li[r] = 0.f; }
#pragma unroll
  for (int dt = 0; dt < 4; dt++) acc[dt] = zf;

  const int nkv = qbase + 16;
  for (int kb = 0; kb < nkv; kb += 32) {
    f32x4 s0 = zf, s1 = zf;
    {
      const bf16x8 k00 = *reinterpret_cast<const bf16x8*>(K + (kb + lr) * 64 + 8 * lg);
      const bf16x8 k01 = *reinterpret_cast<const bf16x8*>(K + (kb + lr) * 64 + 32 + 8 * lg);
      s0 = __builtin_amdgcn_mfma_f32_16x16x32_bf16(qf0, k00, s0, 0, 0, 0);
      s0 = __builtin_amdgcn_mfma_f32_16x16x32_bf16(qf1, k01, s0, 0, 0, 0);
      const bf16x8 k10 = *reinterpret_cast<const bf16x8*>(K + (kb + 16 + lr) * 64 + 8 * lg);
      const bf16x8 k11 = *reinterpret_cast<const bf16x8*>(K + (kb + 16 + lr) * 64 + 32 + 8 * lg);
      s1 = __builtin_amdgcn_mfma_f32_16x16x32_bf16(qf0, k10, s1, 0, 0, 0);
      s1 = __builtin_amdgcn_mfma_f32_16x16x32_bf16(qf1, k11, s1, 0, 0, 0);
    }
    const int key0 = kb + lr, key1 = key0 + 16;
#pragma unroll
    for (int r = 0; r < 4; r++) {
      const int q = qbase + 4 * lg + r;
      float v0 = s0[r] * 0.125f; if (key0 > q) v0 = -1e30f;
      float v1 = s1[r] * 0.125f; if (key1 > q) v1 = -1e30f;
      float mr = fmaxf(v0, v1);
      mr = fmaxf(mr, __shfl_xor(mr, 1));
      mr = fmaxf(mr, __shfl_xor(mr, 2));
      mr = fmaxf(mr, __shfl_xor(mr, 4));
      mr = fmaxf(mr, __shfl_xor(mr, 8));
      const float mnew = fmaxf(mi[r], mr);
      const float alpha = __expf(mi[r] - mnew);
      mi[r] = mnew;
      const float e0 = __expf(v0 - mnew);
      const float e1 = __expf(v1 - mnew);
      float sr = e0 + e1;
      sr += __shfl_xor(sr, 1);
      sr += __shfl_xor(sr, 2);
      sr += __shfl_xor(sr, 4);
      sr += __shfl_xor(sr, 8);
      li[r] = li[r] * alpha + sr;
#pragma unroll
      for (int dt = 0; dt < 4; dt++) acc[dt][r] *= alpha;
      pb[(4 * lg + r) * 32 + lr] = f2bf(e0);
      pb[(4 * lg + r) * 32 + 16 + lr] = f2bf(e1);
    }
    // same-wave LDS RAW: DS ops complete in order; compiler inserts lgkmcnt wait
    const bf16x8 pa = *reinterpret_cast<const bf16x8*>(pb + lr * 32 + 8 * lg);
#pragma unroll
    for (int dt = 0; dt < 4; dt++) {
      const bf16x8 vf = *reinterpret_cast<const bf16x8*>(V + (dt * 16 + lr) * 2048 + kb + 8 * lg);
      acc[dt] = __builtin_amdgcn_mfma_f32_16x16x32_bf16(pa, vf, acc[dt], 0, 0, 0);
    }
  }

#pragma unroll
  for (int dt = 0; dt < 4; dt++) {
    const int d = dt * 16 + lr;
#pragma unroll
    for (int r = 0; r < 4; r++) {
      const int q = qbase + 4 * lg + r;
      y[(b * 2048 + q) * 1024 + h * 64 + d] = acc[dt][r] / li[r];
    }
  }
}

// ---------------------------------------------------------------- launch
extern "C" void kernel_launch(void* const* d_in, const int* in_sizes, int n_in,
                              void* d_out, int out_size, void* d_ws, size_t ws_size,
                              hipStream_t stream) {
  const float* x  = (const float*)d_in[0];
  const float* Wq = (const float*)d_in[1];
  const float* bq = (const float*)d_in[2];
  const float* Wk = (const float*)d_in[3];
  const float* bk = (const float*)d_in[4];
  const float* Wv = (const float*)d_in[5];
  const float* bv = (const float*)d_in[6];

  float* y = (float*)d_out;                 // [B,T,C]      4,194,304
  float* out_k = y + 4194304;               // [B,H,T,D]    4,194,304
  float* out_v = y + 8388608;               // [B,H,T,D]    4,194,304

  char* wsb = (char*)d_ws;                  // 38 MB used
  unsigned short* xbf  = (unsigned short*)(wsb);                    // 8 MB [4096][1024]
  unsigned short* wcat = (unsigned short*)(wsb + (8u  << 20));      // 6 MB [3072][1024]
  unsigned short* qbf  = (unsigned short*)(wsb + (14u << 20));      // 8 MB [BH][T][D]
  unsigned short* kbf  = (unsigned short*)(wsb + (22u << 20));      // 8 MB [BH][T][D]
  unsigned short* vtr  = (unsigned short*)(wsb + (30u << 20));      // 8 MB [BH][D][T]

  cvt_bf16_kernel<<<4096, 256, 0, stream>>>(x, xbf, 4194304);
  cvt_bf16_kernel<<<1024, 256, 0, stream>>>(Wq, wcat, 1048576);
  cvt_bf16_kernel<<<1024, 256, 0, stream>>>(Wk, wcat + 1048576, 1048576);
  cvt_bf16_kernel<<<1024, 256, 0, stream>>>(Wv, wcat + 2097152, 1048576);

  qkv_gemm_kernel<<<dim3(24, 32), 256, 0, stream>>>(xbf, wcat, bq, bk, bv,
                                                    out_k, out_v, qbf, kbf, vtr);

  attn_kernel<<<dim3(32, 32), 256, 0, stream>>>(qbf, kbf, vtr, y);
}

// Round 10
// 259.339 us; speedup vs baseline: 1.4027x; 1.4027x over previous
//
#include <hip/hip_runtime.h>
#include <hip/hip_bf16.h>
#include <stdint.h>

typedef __attribute__((ext_vector_type(8))) short bf16x8;
typedef __attribute__((ext_vector_type(4))) float f32x4;

#define DEVINL __device__ __forceinline__

// ---------------------------------------------------------------- helpers
DEVINL unsigned short f2bf(float f) {
  unsigned int u = __builtin_bit_cast(unsigned int, f);
  u += 0x7fffu + ((u >> 16) & 1u);   // RNE
  return (unsigned short)(u >> 16);
}

DEVINL void gload_lds16(const void* gptr, void* lptr) {
  __builtin_amdgcn_global_load_lds(
      (__attribute__((address_space(1))) void*)(uintptr_t)gptr,
      (__attribute__((address_space(3))) void*)(uint32_t)(uintptr_t)lptr,
      16, 0, 0);
}

// ---------------------------------------------------------------- fp32 -> bf16
__global__ __launch_bounds__(256) void cvt_bf16_kernel(const float* __restrict__ src,
                                                       unsigned short* __restrict__ dst,
                                                       int n) {
  int i = (blockIdx.x * 256 + threadIdx.x) * 4;
  if (i >= n) return;
  const float4 v = *reinterpret_cast<const float4*>(src + i);
  ushort4 o;
  o.x = f2bf(v.x); o.y = f2bf(v.y); o.z = f2bf(v.z); o.w = f2bf(v.w);
  *reinterpret_cast<ushort4*>(dst + i) = o;
}

// ---------------------------------------------------------------- fused QKV GEMM (unchanged)
__global__ __launch_bounds__(256) void qkv_gemm_kernel(
    const unsigned short* __restrict__ xbf,   // [4096][1024] bf16
    const unsigned short* __restrict__ wcat,  // [3072][1024] bf16
    const float* __restrict__ bq,
    const float* __restrict__ bk,
    const float* __restrict__ bv,
    float* __restrict__ out_k,                // [B,H,T,D] f32
    float* __restrict__ out_v,                // [B,H,T,D] f32
    unsigned short* __restrict__ qbf,         // [B,H,T,D] bf16
    unsigned short* __restrict__ kbf,         // [B,H,T,D] bf16
    unsigned short* __restrict__ vtr)         // [B,H,D,T] bf16
{
  __shared__ unsigned short As[128 * 32];
  __shared__ unsigned short Bs[128 * 32];
  const int t = threadIdx.x;
  const int l = t & 63;
  const int w = t >> 6;
  const int lr = l & 15, lg = l >> 4;
  const int wr = w >> 1, wc = w & 1;
  const int m0 = blockIdx.y * 128;
  const int n0 = blockIdx.x * 128;

  const int row0 = (t * 8) >> 5, col0 = (t * 8) & 31;
  const int row1 = ((256 + t) * 8) >> 5, col1 = ((256 + t) * 8) & 31;
  const unsigned short* aG0 = xbf + (m0 + row0) * 1024 + col0;
  const unsigned short* aG1 = xbf + (m0 + row1) * 1024 + col1;
  const unsigned short* bG0 = wcat + (n0 + row0) * 1024 + col0;
  const unsigned short* bG1 = wcat + (n0 + row1) * 1024 + col1;
  unsigned short* aL0 = As + t * 8;
  unsigned short* aL1 = As + (256 + t) * 8;
  unsigned short* bL0 = Bs + t * 8;
  unsigned short* bL1 = Bs + (256 + t) * 8;

  const int aOff = (wr * 64 + lr) * 32 + 8 * lg;
  const int bOff = (wc * 64 + lr) * 32 + 8 * lg;

  f32x4 acc[4][4];
  const f32x4 zf = {0.f, 0.f, 0.f, 0.f};
#pragma unroll
  for (int i = 0; i < 4; i++)
#pragma unroll
    for (int j = 0; j < 4; j++) acc[i][j] = zf;

  for (int kt = 0; kt < 1024; kt += 32) {
    gload_lds16(aG0 + kt, aL0);
    gload_lds16(aG1 + kt, aL1);
    gload_lds16(bG0 + kt, bL0);
    gload_lds16(bG1 + kt, bL1);
    __syncthreads();
    bf16x8 af[4], bfr[4];
#pragma unroll
    for (int mi = 0; mi < 4; mi++)
      af[mi] = *reinterpret_cast<const bf16x8*>(As + aOff + mi * 16 * 32);
#pragma unroll
    for (int ni = 0; ni < 4; ni++)
      bfr[ni] = *reinterpret_cast<const bf16x8*>(Bs + bOff + ni * 16 * 32);
#pragma unroll
    for (int mi = 0; mi < 4; mi++)
#pragma unroll
      for (int ni = 0; ni < 4; ni++)
        acc[mi][ni] = __builtin_amdgcn_mfma_f32_16x16x32_bf16(af[mi], bfr[ni], acc[mi][ni], 0, 0, 0);
    __syncthreads();
  }

  const int which = n0 >> 10;
  const float* bias = (which == 0) ? bq : (which == 1) ? bk : bv;
#pragma unroll
  for (int ni = 0; ni < 4; ni++) {
    const int n = n0 + wc * 64 + ni * 16 + lr;
    const int co = n & 1023;
    const float bb = bias[co];
    const int h = co >> 6, d = co & 63;
#pragma unroll
    for (int mi = 0; mi < 4; mi++) {
#pragma unroll
      for (int r = 0; r < 4; r++) {
        const int m = m0 + wr * 64 + mi * 16 + 4 * lg + r;
        const float val = acc[mi][ni][r] + bb;
        const int bb_ = m >> 11, tt = m & 2047;
        const int bh = bb_ * 16 + h;
        const int idx = (bh * 2048 + tt) * 64 + d;
        if (which == 0) {
          qbf[idx] = f2bf(val);
        } else if (which == 1) {
          out_k[idx] = val;
          kbf[idx] = f2bf(val);
        } else {
          out_v[idx] = val;
          vtr[(bh * 64 + d) * 2048 + tt] = f2bf(val);
        }
      }
    }
  }
}

// ---------------------------------------------------------------- flash attention v2
// 8 waves/block (512 thr). Waves 0-3 -> q-tile p, waves 4-7 -> q-tile 31-p
// (uniform work per block). Swapped QK^T: S^T = mfma(K, Q) puts a full score
// row (q = lane&15) in-lane -> softmax = in-lane tree + 2 shfl. KVBLK=64.
// PV: y^T = V^T * P^T, P^T bounced via LDS [q][64keys] pad-80.
__global__ __launch_bounds__(512) void attn_kernel(
    const unsigned short* __restrict__ qbf,  // [BH][T][D] bf16
    const unsigned short* __restrict__ kbf,  // [BH][T][D] bf16
    const unsigned short* __restrict__ vtr,  // [BH][D][T] bf16
    float* __restrict__ y)                   // [B,T,C] f32
{
  __shared__ unsigned short pbuf[8][16 * 80];
  const int w = threadIdx.x >> 6, l = threadIdx.x & 63;
  const int lr = l & 15, lg = l >> 4;

  // XCD-swizzle: xcd = blk&7 owns heads {4*xcd .. 4*xcd+3} -> K/V L2-resident
  const int blk = blockIdx.x;
  const int xcd = blk & 7, slot = blk >> 3;     // slot 0..63
  const int bh = xcd * 4 + (slot & 3);          // 0..31
  const int p = slot >> 2;                      // 0..15
  const int qt = (w < 4) ? p : (31 - p);
  const int qbase = qt * 64 + (w & 3) * 16;
  const int b = bh >> 4, h = bh & 15;

  const unsigned short* Q = qbf + bh * 2048 * 64;
  const unsigned short* K = kbf + bh * 2048 * 64;
  const unsigned short* V = vtr + bh * 64 * 2048;
  unsigned short* pb = pbuf[w];

  const int qrow = qbase + lr;                  // this lane's q row
  const bf16x8 qf0 = *reinterpret_cast<const bf16x8*>(Q + qrow * 64 + 8 * lg);
  const bf16x8 qf1 = *reinterpret_cast<const bf16x8*>(Q + qrow * 64 + 32 + 8 * lg);

  float mi = -1e30f, li = 0.f;
  f32x4 acc[4];
  const f32x4 zf = {0.f, 0.f, 0.f, 0.f};
#pragma unroll
  for (int dt = 0; dt < 4; dt++) acc[dt] = zf;

  const int nkv = qbase + 16;
  for (int kb = 0; kb < nkv; kb += 64) {
    // ---- QK^T swapped: S^T[key][q], lane holds 16 keys for q=lr
    f32x4 s[4];
#pragma unroll
    for (int kt = 0; kt < 4; kt++) {
      const unsigned short* kr = K + (kb + kt * 16 + lr) * 64;
      const bf16x8 kf0 = *reinterpret_cast<const bf16x8*>(kr + 8 * lg);
      const bf16x8 kf1 = *reinterpret_cast<const bf16x8*>(kr + 32 + 8 * lg);
      f32x4 t = zf;
      t = __builtin_amdgcn_mfma_f32_16x16x32_bf16(kf0, qf0, t, 0, 0, 0);
      t = __builtin_amdgcn_mfma_f32_16x16x32_bf16(kf1, qf1, t, 0, 0, 0);
      s[kt] = t;
    }
    // ---- scale + causal mask (key = kb + kt*16 + 4*lg + r)
    float v[16];
#pragma unroll
    for (int kt = 0; kt < 4; kt++)
#pragma unroll
      for (int r = 0; r < 4; r++) {
        const int key = kb + kt * 16 + 4 * lg + r;
        const float val = s[kt][r] * 0.125f;
        v[kt * 4 + r] = (key > qrow) ? -1e30f : val;
      }
    // ---- row max: in-lane tree + 2 shfl (across lg groups)
    float t8[8];
#pragma unroll
    for (int i = 0; i < 8; i++) t8[i] = fmaxf(v[2 * i], v[2 * i + 1]);
    float t4[4];
#pragma unroll
    for (int i = 0; i < 4; i++) t4[i] = fmaxf(t8[2 * i], t8[2 * i + 1]);
    float mr = fmaxf(fmaxf(t4[0], t4[1]), fmaxf(t4[2], t4[3]));
    mr = fmaxf(mr, __shfl_xor(mr, 16));
    mr = fmaxf(mr, __shfl_xor(mr, 32));
    const float mnew = fmaxf(mi, mr);
    const float alpha = __expf(mi - mnew);
    mi = mnew;
    // ---- exp + row sum
#pragma unroll
    for (int i = 0; i < 16; i++) v[i] = __expf(v[i] - mnew);
    float s8[8];
#pragma unroll
    for (int i = 0; i < 8; i++) s8[i] = v[2 * i] + v[2 * i + 1];
    float s4[4];
#pragma unroll
    for (int i = 0; i < 4; i++) s4[i] = s8[2 * i] + s8[2 * i + 1];
    float sr = (s4[0] + s4[1]) + (s4[2] + s4[3]);
    sr += __shfl_xor(sr, 16);
    sr += __shfl_xor(sr, 32);
    li = li * alpha + sr;
#pragma unroll
    for (int dt = 0; dt < 4; dt++)
#pragma unroll
      for (int r = 0; r < 4; r++) acc[dt][r] *= alpha;
    // ---- P^T -> LDS as [q=lr][key], pad 80 shorts/row; packed u32 writes
#pragma unroll
    for (int kt = 0; kt < 4; kt++)
#pragma unroll
      for (int i = 0; i < 2; i++) {
        const unsigned int pk =
            ((unsigned int)f2bf(v[kt * 4 + 2 * i + 1]) << 16) | f2bf(v[kt * 4 + 2 * i]);
        *reinterpret_cast<unsigned int*>(pb + lr * 80 + kt * 16 + 4 * lg + 2 * i) = pk;
      }
    // same-wave LDS RAW: DS completes in order; compiler inserts lgkmcnt
    const bf16x8 pf0 = *reinterpret_cast<const bf16x8*>(pb + lr * 80 + 8 * lg);
    const bf16x8 pf1 = *reinterpret_cast<const bf16x8*>(pb + lr * 80 + 32 + 8 * lg);
    // ---- PV: y^T[d][q] += V^T[d][key] * P^T[key][q]
#pragma unroll
    for (int dt = 0; dt < 4; dt++) {
      const unsigned short* vr = V + (dt * 16 + lr) * 2048 + kb;
      const bf16x8 vf0 = *reinterpret_cast<const bf16x8*>(vr + 8 * lg);
      const bf16x8 vf1 = *reinterpret_cast<const bf16x8*>(vr + 32 + 8 * lg);
      acc[dt] = __builtin_amdgcn_mfma_f32_16x16x32_bf16(vf0, pf0, acc[dt], 0, 0, 0);
      acc[dt] = __builtin_amdgcn_mfma_f32_16x16x32_bf16(vf1, pf1, acc[dt], 0, 0, 0);
    }
  }

  // ---- epilogue: lane holds y[qrow][d], d = dt*16 + 4*lg + r (r contiguous)
  const float inv = 1.0f / li;
  float* yb = y + (b * 2048 + qrow) * 1024 + h * 64;
#pragma unroll
  for (int dt = 0; dt < 4; dt++) {
    float4 o;
    o.x = acc[dt][0] * inv; o.y = acc[dt][1] * inv;
    o.z = acc[dt][2] * inv; o.w = acc[dt][3] * inv;
    *reinterpret_cast<float4*>(yb + dt * 16 + 4 * lg) = o;
  }
}

// ---------------------------------------------------------------- launch
extern "C" void kernel_launch(void* const* d_in, const int* in_sizes, int n_in,
                              void* d_out, int out_size, void* d_ws, size_t ws_size,
                              hipStream_t stream) {
  const float* x  = (const float*)d_in[0];
  const float* Wq = (const float*)d_in[1];
  const float* bq = (const float*)d_in[2];
  const float* Wk = (const float*)d_in[3];
  const float* bk = (const float*)d_in[4];
  const float* Wv = (const float*)d_in[5];
  const float* bv = (const float*)d_in[6];

  float* y = (float*)d_out;                 // [B,T,C]      4,194,304
  float* out_k = y + 4194304;               // [B,H,T,D]    4,194,304
  float* out_v = y + 8388608;               // [B,H,T,D]    4,194,304

  char* wsb = (char*)d_ws;                  // 38 MB used
  unsigned short* xbf  = (unsigned short*)(wsb);                    // 8 MB [4096][1024]
  unsigned short* wcat = (unsigned short*)(wsb + (8u  << 20));      // 6 MB [3072][1024]
  unsigned short* qbf  = (unsigned short*)(wsb + (14u << 20));      // 8 MB [BH][T][D]
  unsigned short* kbf  = (unsigned short*)(wsb + (22u << 20));      // 8 MB [BH][T][D]
  unsigned short* vtr  = (unsigned short*)(wsb + (30u << 20));      // 8 MB [BH][D][T]

  cvt_bf16_kernel<<<4096, 256, 0, stream>>>(x, xbf, 4194304);
  cvt_bf16_kernel<<<1024, 256, 0, stream>>>(Wq, wcat, 1048576);
  cvt_bf16_kernel<<<1024, 256, 0, stream>>>(Wk, wcat + 1048576, 1048576);
  cvt_bf16_kernel<<<1024, 256, 0, stream>>>(Wv, wcat + 2097152, 1048576);

  qkv_gemm_kernel<<<dim3(24, 32), 256, 0, stream>>>(xbf, wcat, bq, bk, bv,
                                                    out_k, out_v, qbf, kbf, vtr);

  attn_kernel<<<512, 512, 0, stream>>>(qbf, kbf, vtr, y);
}